// Round 16
// baseline (457.741 us; speedup 1.0000x reference)
//
#include <hip/hip_runtime.h>
#include <math.h>

// Problem constants
#define BB 16
#define CC 256
#define HH 128
#define WW 128
#define HWSZ 16384        // H*W
#define NF 8
#define EPSV 1e-5f

typedef __attribute__((ext_vector_type(8))) short short8;   // 8 bf16 = 4 VGPRs
typedef __attribute__((ext_vector_type(4))) float f32x4;

static __device__ __forceinline__ unsigned short f2bf(float f) {
  unsigned int u = __float_as_uint(f);
  u += 0x7fffu + ((u >> 16) & 1u);       // round-to-nearest-even
  return (unsigned short)(u >> 16);
}

static __device__ __forceinline__ float bf2f(unsigned int h) {
  return __uint_as_float(h << 16);
}

static __device__ __forceinline__ void gload_lds16(const unsigned short* g,
                                                   unsigned short* l) {
  __builtin_amdgcn_global_load_lds(
      (const __attribute__((address_space(1))) void*)(size_t)g,
      (__attribute__((address_space(3))) void*)(unsigned)(size_t)l, 16, 0, 0);
}

// ---------------------------------------------------------------------------
// K1: fused  (a) pooled[b,c] = mean over HW   (blocks 0..4095)
//            (b) pack proj_w -> bf16 A-frag order (blocks 4096..4351)
// ---------------------------------------------------------------------------
__global__ __launch_bounds__(256) void pool_pack_kernel(
    const float* __restrict__ x, const float* __restrict__ pw,
    float* __restrict__ pooled, unsigned short* __restrict__ ap) {
  int blk = blockIdx.x;
  int tid = threadIdx.x;
  if (blk >= BB * CC) {            // pack_a part
    int idx = (blk - BB * CC) * 256 + tid;      // 0..65535
    int e = idx & 7;
    int lane = (idx >> 3) & 63;
    int kb = (idx >> 9) & 7;
    int mb = idx >> 12;
    int o = mb * 16 + (lane & 15);
    int c = kb * 32 + (lane >> 4) * 8 + e;
    ap[idx] = f2bf(pw[o * 256 + c]);
    return;
  }
  // pool part
  const float4* xp = (const float4*)(x + (size_t)blk * HWSZ);
  float s = 0.f;
#pragma unroll
  for (int i = 0; i < 16; ++i) {
    float4 v = xp[tid + i * 256];
    s += v.x + v.y + v.z + v.w;
  }
#pragma unroll
  for (int off = 32; off > 0; off >>= 1) s += __shfl_down(s, off, 64);
  __shared__ float ls[4];
  if ((tid & 63) == 0) ls[tid >> 6] = s;
  __syncthreads();
  if (tid == 0) pooled[blk] = (ls[0] + ls[1] + ls[2] + ls[3]) * (1.0f / 16384.0f);
}

// ---------------------------------------------------------------------------
// K3: depthwise 7x7 conv + IN-BLOCK selector (redundant per block, L2-hot):
//     logits via 64-thread dot + 8-lane shuffle tree; softmax on thread 0;
//     49-tap mix on threads 0..48. Removes the 1-block selector kernel.
//     TR=64, thread = 8 rows x 4 cols; fp32 compute, bf16 output.
// ---------------------------------------------------------------------------
#define TR 64
__global__ __launch_bounds__(256) void dwconv_kernel(
    const float* __restrict__ x, const float* __restrict__ pooled,
    const float* __restrict__ sel_w, const float* __restrict__ sel_b,
    const float* __restrict__ fbank, unsigned short* __restrict__ fbp) {
  int plane = blockIdx.x;          // b*256 + c
  int rt = blockIdx.y;             // 0..1
  int b = plane >> 8;
  int r0 = rt * TR;
  int tid = threadIdx.x;

  __shared__ float xs[TR + 6][136];
  __shared__ float wsm[NF];
  __shared__ float cmb[64];

  // ---- stage x tile (all threads; completes before first barrier)
  const size_t pbase = (size_t)plane * HWSZ;
  for (int idx = tid; idx < (TR + 6) * 34; idx += 256) {
    int row = idx / 34;            // 0..69
    int seg = idx % 34;
    int r = r0 - 3 + row;
    int c = seg * 4 - 4;
    float4 v = make_float4(0.f, 0.f, 0.f, 0.f);
    if (r >= 0 && r < HH && c >= 0 && c < WW) {
      v = *(const float4*)(x + pbase + (size_t)r * WW + c);
    }
    *(float4*)&xs[row][seg * 4] = v;
  }

  // ---- selector: logits (threads 0..63, one wave)
  if (tid < 64) {
    int n = tid >> 3, ck = tid & 7;
    const float* p = pooled + b * CC + ck * 32;
    const float* w = sel_w + n * CC + ck * 32;
    float d = 0.f;
#pragma unroll
    for (int i = 0; i < 32; ++i) d += p[i] * w[i];
    d += __shfl_down(d, 4, 8);
    d += __shfl_down(d, 2, 8);
    d += __shfl_down(d, 1, 8);
    if (ck == 0) wsm[n] = d + sel_b[n];   // logits (pre-softmax)
  }
  __syncthreads();
  if (tid == 0) {
    float m = wsm[0];
#pragma unroll
    for (int n = 1; n < NF; ++n) m = fmaxf(m, wsm[n]);
    float e[NF];
    float s = 0.f;
#pragma unroll
    for (int n = 0; n < NF; ++n) { e[n] = expf(wsm[n] - m); s += e[n]; }
    float inv = 1.0f / s;
#pragma unroll
    for (int n = 0; n < NF; ++n) wsm[n] = e[n] * inv;
  }
  __syncthreads();
  if (tid < 49) {
    float a = 0.f;
#pragma unroll
    for (int n = 0; n < NF; ++n) a += wsm[n] * fbank[n * 49 + tid];
    cmb[tid] = a;
  }
  __syncthreads();                 // cmb ready; xs also ready (staged pre-bar1)

  float kf[49];
#pragma unroll
  for (int i = 0; i < 49; ++i) kf[i] = cmb[i];

  int cg = tid & 31;               // col group: cols 4cg..4cg+3
  int rg = tid >> 5;               // row group: rows 8rg..8rg+7 (rel to r0)
  float acc[8][4] = {};

#pragma unroll
  for (int ri = 0; ri < 14; ++ri) {          // input rows 8rg-3 .. 8rg+10
    int lrow = 8 * rg + ri;                  // LDS row index
    float xr[12];
#pragma unroll
    for (int s = 0; s < 3; ++s)
      *(float4*)&xr[4 * s] = *(const float4*)&xs[lrow][cg * 4 + 4 * s];
#pragma unroll
    for (int orr = 0; orr < 8; ++orr) {
      int dy = ri - orr;
      if (dy < 0 || dy > 6) continue;        // compile-time pruned
#pragma unroll
      for (int oc = 0; oc < 4; ++oc) {
#pragma unroll
        for (int dx = 0; dx < 7; ++dx) {
          acc[orr][oc] += xr[oc + dx + 1] * kf[dy * 7 + dx];
        }
      }
    }
  }

#pragma unroll
  for (int orr = 0; orr < 8; ++orr) {
    ushort4 sv;
    sv.x = f2bf(acc[orr][0]);
    sv.y = f2bf(acc[orr][1]);
    sv.z = f2bf(acc[orr][2]);
    sv.w = f2bf(acc[orr][3]);
    *(ushort4*)(fbp + pbase + (size_t)(r0 + 8 * rg + orr) * WW + 4 * cg) = sv;
  }
}

// ---------------------------------------------------------------------------
// K4: 1x1 conv as bf16 MFMA GEMM — in-kernel B repack, 3-buffer LDS pipeline,
//     ONE barrier per K-step, B reg-prefetch 3 deep, setprio'd MFMA (T5),
//     epilogue LDS-bounce for fully-coalesced 16B y stores (r5/r6-proven).
//     Block = 256 o x 128 p, 512 thr (8 waves = 4 wm x 2 wn, each 64o x 64p).
// ---------------------------------------------------------------------------
#define SWZ(p) ((((p) >> 1) ^ ((p) >> 4)) & 3)

__global__ __launch_bounds__(512, 2) void gemm_kernel(
    const unsigned short* __restrict__ fb, const unsigned short* __restrict__ ap,
    const float* __restrict__ proj_b, unsigned short* __restrict__ yb,
    float* __restrict__ part) {
  int bid = blockIdx.x;            // bs*128 + pt
  int bs = bid >> 7;
  int pt = bid & 127;
  int p0 = pt * 128;
  int tid = threadIdx.x;
  int lane = tid & 63;
  int wave = tid >> 6;
  int wm = wave >> 1;              // 0..3 -> o 64-block
  int wn = wave & 1;               // 0..1 -> p 64-block

  // unified LDS: panels (48K A + 24K B) reused as epilogue bounce (8x64x72)
  __shared__ __align__(16) unsigned char smem[73728];
  unsigned short (*A_lds)[8192] = (unsigned short (*)[8192])smem;          // 3 bufs
  unsigned short (*B_lds)[4096] = (unsigned short (*)[4096])(smem + 49152);// 3 bufs

  // --- A staging: thread t stages MB=(t>>6) and MB=8+(t>>6)
  const unsigned short* asrc0 =
      ap + (size_t)(tid >> 6) * 4096 + (size_t)(tid & 63) * 8;
  unsigned short* adst = &A_lds[0][0] + (size_t)tid * 8;

  // --- B staging: thread t reg-loads c rows {2cp,2cp+1}, p = 4pq..4pq+3
  int cp = tid >> 5;               // 0..15
  int pq = tid & 31;               // 0..31
  const unsigned short* bsrc0 =
      fb + ((size_t)bs * CC + 2 * cp) * HWSZ + p0 + 4 * pq;

  uint2 bregs[4][2];               // [slot = kb&3][row]

#define STAGE_A(kb, buf)                                                      \
  do {                                                                        \
    gload_lds16(asrc0 + (size_t)(kb) * 512, adst + (size_t)(buf) * 8192);     \
    gload_lds16(asrc0 + 32768 + (size_t)(kb) * 512,                           \
                adst + (size_t)(buf) * 8192 + 4096);                          \
  } while (0)
#define LOAD_B(kb, slot)                                                      \
  do {                                                                        \
    const unsigned short* s_ = bsrc0 + (size_t)(kb) * 32 * HWSZ;              \
    bregs[slot][0] = *(const uint2*)s_;                                       \
    bregs[slot][1] = *(const uint2*)(s_ + HWSZ);                              \
  } while (0)
#define WRITE_B(slot, buf)                                                    \
  do {                                                                        \
    unsigned int w0_[2] = {bregs[slot][0].x, bregs[slot][0].y};               \
    unsigned int w1_[2] = {bregs[slot][1].x, bregs[slot][1].y};               \
    _Pragma("unroll")                                                         \
    for (int j_ = 0; j_ < 4; ++j_) {                                          \
      int p_ = 4 * pq + j_;                                                   \
      int cc_ = (2 * cp) ^ (SWZ(p_) << 3);                                    \
      unsigned int lo_ = (w0_[j_ >> 1] >> ((j_ & 1) * 16)) & 0xffffu;         \
      unsigned int hi_ = (w1_[j_ >> 1] >> ((j_ & 1) * 16)) & 0xffffu;         \
      *(unsigned int*)&B_lds[buf][p_ * 32 + cc_] = lo_ | (hi_ << 16);         \
    }                                                                         \
  } while (0)

  // ---- prologue: FIFO order A0,B0,A1,B1,B2 (10 vm ops)
  STAGE_A(0, 0);
  LOAD_B(0, 0);
  STAGE_A(1, 1);
  LOAD_B(1, 1);
  LOAD_B(2, 2);

  f32x4 acc[4][4];
#pragma unroll
  for (int mb = 0; mb < 4; ++mb)
#pragma unroll
    for (int nb = 0; nb < 4; ++nb) acc[mb][nb] = (f32x4){0.f, 0.f, 0.f, 0.f};

  // LDS read offsets (elements)
  int aofs[4];
#pragma unroll
  for (int mb = 0; mb < 4; ++mb) aofs[mb] = ((wm * 4 + mb) * 64 + lane) * 8;
  int bofs[4];
#pragma unroll
  for (int nb = 0; nb < 4; ++nb) {
    int pp = wn * 64 + nb * 16 + (lane & 15);
    bofs[nb] = pp * 32 + (((lane >> 4) * 8) ^ (SWZ(pp) << 3));
  }

  // retire A0+B0 (oldest 4 of 10), publish B(0)
  asm volatile("s_waitcnt vmcnt(6)" ::: "memory");
  WRITE_B(0, 0);
  asm volatile("s_waitcnt lgkmcnt(0)" ::: "memory");
  __builtin_amdgcn_s_barrier();              // panel 0 published

#pragma unroll
  for (int kb = 0; kb < 8; ++kb) {
    const int cur = kb % 3;
    const int n1 = (kb + 1) % 3;
    // 1. issue A(kb+2) into LDS buf (kb+2)%3 (released at barrier kb-1),
    //    then B(kb+3) into reg slot (kb+3)&3
    if (kb < 6) STAGE_A(kb + 2, (kb + 2) % 3);
    if (kb < 5) LOAD_B(kb + 3, (kb + 3) & 3);
    if (kb < 6) __builtin_amdgcn_sched_barrier(0);
    // 2. read fragments of panel kb (published)
    short8 af[4], bfr[4];
#pragma unroll
    for (int mb = 0; mb < 4; ++mb)
      af[mb] = *(const short8*)(&A_lds[cur][0] + aofs[mb]);
#pragma unroll
    for (int nb = 0; nb < 4; ++nb)
      bfr[nb] = *(const short8*)(&B_lds[cur][0] + bofs[nb]);
    // 3. retire A(kb+1) [LDS] + B(kb+1) [regs, issued kb-2], publish B(kb+1)
    if (kb <= 4) {
      asm volatile("s_waitcnt vmcnt(6)" ::: "memory");
      WRITE_B((kb + 1) & 3, n1);
    } else if (kb == 5) {
      asm volatile("s_waitcnt vmcnt(4)" ::: "memory");
      WRITE_B((kb + 1) & 3, n1);
    } else if (kb == 6) {
      asm volatile("s_waitcnt vmcnt(0)" ::: "memory");
      WRITE_B((kb + 1) & 3, n1);
    }
    // 4. all LDS ops (frag reads + B writes) complete
    asm volatile("s_waitcnt lgkmcnt(0)" ::: "memory");
    __builtin_amdgcn_sched_barrier(0);
    // 5. MFMA on panel kb (T5)
    __builtin_amdgcn_s_setprio(1);
#pragma unroll
    for (int mb = 0; mb < 4; ++mb)
#pragma unroll
      for (int nb = 0; nb < 4; ++nb)
        acc[mb][nb] = __builtin_amdgcn_mfma_f32_16x16x32_bf16(
            af[mb], bfr[nb], acc[mb][nb], 0, 0, 0);
    __builtin_amdgcn_s_setprio(0);
    // 6. single barrier: publishes panel kb+1, releases buf cur
    if (kb < 7) __builtin_amdgcn_s_barrier();
  }

  // all waves' panel reads done -> smem reusable as bounce
  __builtin_amdgcn_s_barrier();

  // ---- epilogue: bias, GN partials, LDS bounce, coalesced 16B y stores
  // C/D layout: col(p) = lane&15, row(o) = (lane>>4)*4 + reg
  unsigned short* yt = (unsigned short*)smem + (size_t)wave * 4608;  // 64x72
  float psum[2] = {0.f, 0.f}, psq[2] = {0.f, 0.f};
  int orl = (lane >> 4) * 4;
  int pl = lane & 15;
#pragma unroll
  for (int mb = 0; mb < 4; ++mb) {
    int gi = mb >> 1;                        // wave covers 2 GN groups (64 ch)
#pragma unroll
    for (int r = 0; r < 4; ++r) {
      int ol = mb * 16 + orl + r;
      float pb = proj_b[wm * 64 + ol];
#pragma unroll
      for (int nb = 0; nb < 4; ++nb) {
        float v = acc[mb][nb][r] + pb;
        yt[ol * 72 + pl + nb * 16] = f2bf(v);
        psum[gi] += v;
        psq[gi] += v * v;
      }
    }
  }
  // wave-private bounce: same-wave ds_write->ds_read ordered by lgkmcnt
  const size_t ybase = (size_t)bs * CC * HWSZ + p0 + wn * 64;
#pragma unroll
  for (int k = 0; k < 8; ++k) {
    int idx = k * 64 + lane;
    int ol = idx >> 3, ch = idx & 7;
    uint4 v = *(const uint4*)(yt + ol * 72 + ch * 8);
    *(uint4*)(yb + ybase + (size_t)(wm * 64 + ol) * HWSZ + ch * 8) = v;
  }

#pragma unroll
  for (int off = 32; off > 0; off >>= 1) {
#pragma unroll
    for (int k = 0; k < 2; ++k) {
      psum[k] += __shfl_down(psum[k], off, 64);
      psq[k] += __shfl_down(psq[k], off, 64);
    }
  }
  if (lane == 0) {
#pragma unroll
    for (int k = 0; k < 2; ++k) {
      int bg = bs * 8 + wm * 2 + k;
      part[(size_t)bg * 256 + pt * 2 + wn] = psum[k];
      part[32768 + (size_t)bg * 256 + pt * 2 + wn] = psq[k];
    }
  }
#undef STAGE_A
#undef LOAD_B
#undef WRITE_B
}

// ---------------------------------------------------------------------------
// K5: GroupNorm affine + exact GELU + residual, with IN-KERNEL stats reduce.
//     Reads bf16 y, writes fp32 out.
// ---------------------------------------------------------------------------
__global__ __launch_bounds__(256) void out_kernel(
    const float* __restrict__ x, const unsigned short* __restrict__ yb,
    const float* __restrict__ part, const float* __restrict__ gamma,
    const float* __restrict__ beta, float* __restrict__ out) {
  int plane = blockIdx.x;
  int b = plane >> 8, c = plane & 255, g = c >> 5;
  int bg = b * 8 + g;
  int t = threadIdx.x;

  // reduce this group's 256 partials (all threads participate)
  float s = part[(size_t)bg * 256 + t];
  float q = part[32768 + (size_t)bg * 256 + t];
#pragma unroll
  for (int off = 32; off > 0; off >>= 1) {
    s += __shfl_down(s, off, 64);
    q += __shfl_down(q, off, 64);
  }
  __shared__ float ls[8];
  if ((t & 63) == 0) { ls[t >> 6] = s; ls[4 + (t >> 6)] = q; }
  __syncthreads();
  float tsum = ls[0] + ls[1] + ls[2] + ls[3];
  float tsq = ls[4] + ls[5] + ls[6] + ls[7];

  const float inv_n = 1.0f / (32.0f * (float)HWSZ);
  float mean = tsum * inv_n;
  float var = tsq * inv_n - mean * mean;
  float rstd = rsqrtf(var + EPSV);
  float scale = gamma[c] * rstd;
  float shift = beta[c] - mean * scale;

  const size_t base = (size_t)plane * HWSZ;
  for (int i = t; i < HWSZ / 8; i += 256) {
    uint4 yv = *(const uint4*)(yb + base + 8 * (size_t)i);
    float4 x0 = *(const float4*)(x + base + 8 * (size_t)i);
    float4 x1 = *(const float4*)(x + base + 8 * (size_t)i + 4);
    unsigned int yw[4] = {yv.x, yv.y, yv.z, yv.w};
    float r[8];
    float xr[8] = {x0.x, x0.y, x0.z, x0.w, x1.x, x1.y, x1.z, x1.w};
#pragma unroll
    for (int k = 0; k < 8; ++k) {
      unsigned int h = (yw[k >> 1] >> ((k & 1) * 16)) & 0xffffu;
      float tv = bf2f(h) * scale + shift;
      float ge = 0.5f * tv * (1.0f + erff(tv * 0.70710678118654752f));
      r[k] = ge + xr[k];
    }
    *(float4*)(out + base + 8 * (size_t)i) = make_float4(r[0], r[1], r[2], r[3]);
    *(float4*)(out + base + 8 * (size_t)i + 4) = make_float4(r[4], r[5], r[6], r[7]);
  }
}

// ---------------------------------------------------------------------------
extern "C" void kernel_launch(void* const* d_in, const int* in_sizes, int n_in,
                              void* d_out, int out_size, void* d_ws, size_t ws_size,
                              hipStream_t stream) {
  const float* x      = (const float*)d_in[0];
  const float* fbank  = (const float*)d_in[1];   // [NF,1,7,7]
  const float* sel_w  = (const float*)d_in[2];   // [NF,C]
  const float* sel_b  = (const float*)d_in[3];   // [NF]
  const float* proj_w = (const float*)d_in[4];   // [C,C,1,1]
  const float* proj_b = (const float*)d_in[5];   // [C]
  const float* gamma  = (const float*)d_in[6];   // [C]
  const float* beta   = (const float*)d_in[7];   // [C]
  float* out = (float*)d_out;

  // ws layout: fb bf16 [B*C*HW] | yb bf16 [B*C*HW] (distinct: gemm reads fb!)
  //            | ap bf16 [65536] | pooled | part[65536]
  unsigned short* fb  = (unsigned short*)d_ws;
  unsigned short* yb  = fb + (size_t)BB * CC * HWSZ;
  unsigned short* apk = yb + (size_t)BB * CC * HWSZ;
  float* pooled   = (float*)(apk + 65536);
  float* part     = pooled + BB * CC;

  hipLaunchKernelGGL(pool_pack_kernel, dim3(BB * CC + 256), dim3(256), 0, stream,
                     x, proj_w, pooled, apk);
  hipLaunchKernelGGL(dwconv_kernel, dim3(BB * CC, HH / TR), dim3(256), 0, stream,
                     x, pooled, sel_w, sel_b, fbank, fb);
  hipLaunchKernelGGL(gemm_kernel, dim3(BB * 128), dim3(512), 0, stream,
                     fb, apk, proj_b, yb, part);
  hipLaunchKernelGGL(out_kernel, dim3(BB * CC), dim3(256), 0, stream,
                     x, yb, part, gamma, beta, out);
}

// Round 17
// 430.272 us; speedup vs baseline: 1.0638x; 1.0638x over previous
//
#include <hip/hip_runtime.h>
#include <math.h>

// Problem constants
#define BB 16
#define CC 256
#define HH 128
#define WW 128
#define HWSZ 16384        // H*W
#define NF 8
#define EPSV 1e-5f

typedef __attribute__((ext_vector_type(8))) short short8;   // 8 bf16 = 4 VGPRs
typedef __attribute__((ext_vector_type(4))) float f32x4;

static __device__ __forceinline__ unsigned short f2bf(float f) {
  unsigned int u = __float_as_uint(f);
  u += 0x7fffu + ((u >> 16) & 1u);       // round-to-nearest-even
  return (unsigned short)(u >> 16);
}

static __device__ __forceinline__ float bf2f(unsigned int h) {
  return __uint_as_float(h << 16);
}

static __device__ __forceinline__ void gload_lds16(const unsigned short* g,
                                                   unsigned short* l) {
  __builtin_amdgcn_global_load_lds(
      (const __attribute__((address_space(1))) void*)(size_t)g,
      (__attribute__((address_space(3))) void*)(unsigned)(size_t)l, 16, 0, 0);
}

// ---------------------------------------------------------------------------
// K1: fused  (a) pooled[b,c] = mean over HW + xb = bf16(x)  (blocks 0..4095)
//            (b) pack proj_w -> bf16 A-frag order (blocks 4096..4351)
//     xb lives in d_out (dead until out_kernel overwrites it).
// ---------------------------------------------------------------------------
__global__ __launch_bounds__(256) void pool_pack_kernel(
    const float* __restrict__ x, const float* __restrict__ pw,
    float* __restrict__ pooled, unsigned short* __restrict__ ap,
    unsigned short* __restrict__ xb) {
  int blk = blockIdx.x;
  int tid = threadIdx.x;
  if (blk >= BB * CC) {            // pack_a part
    int idx = (blk - BB * CC) * 256 + tid;      // 0..65535
    int e = idx & 7;
    int lane = (idx >> 3) & 63;
    int kb = (idx >> 9) & 7;
    int mb = idx >> 12;
    int o = mb * 16 + (lane & 15);
    int c = kb * 32 + (lane >> 4) * 8 + e;
    ap[idx] = f2bf(pw[o * 256 + c]);
    return;
  }
  // pool + bf16-cast part
  const float4* xp = (const float4*)(x + (size_t)blk * HWSZ);
  ushort4* xbp = (ushort4*)(xb + (size_t)blk * HWSZ);
  float s = 0.f;
#pragma unroll
  for (int i = 0; i < 16; ++i) {
    float4 v = xp[tid + i * 256];
    s += v.x + v.y + v.z + v.w;
    ushort4 bv;
    bv.x = f2bf(v.x);
    bv.y = f2bf(v.y);
    bv.z = f2bf(v.z);
    bv.w = f2bf(v.w);
    xbp[tid + i * 256] = bv;
  }
#pragma unroll
  for (int off = 32; off > 0; off >>= 1) s += __shfl_down(s, off, 64);
  __shared__ float ls[4];
  if ((tid & 63) == 0) ls[tid >> 6] = s;
  __syncthreads();
  if (tid == 0) pooled[blk] = (ls[0] + ls[1] + ls[2] + ls[3]) * (1.0f / 16384.0f);
}

// ---------------------------------------------------------------------------
// K2: selector: GAP -> linear -> softmax -> mix filter bank. (r15-proven)
// ---------------------------------------------------------------------------
__global__ __launch_bounds__(256) void selector_kernel(
    const float* __restrict__ pooled, const float* __restrict__ sel_w,
    const float* __restrict__ sel_b, const float* __restrict__ fbank,
    float* __restrict__ combined) {
  int tid = threadIdx.x;
  __shared__ float lg[BB][NF];
  __shared__ float wsm[BB][NF];
  if (tid < BB * NF) {
    int b = tid >> 3, n = tid & 7;
    const float* p = pooled + b * CC;
    const float* w = sel_w + n * CC;
    float d = sel_b[n];
    for (int c = 0; c < CC; c += 4) {
      d += p[c] * w[c] + p[c + 1] * w[c + 1] + p[c + 2] * w[c + 2] + p[c + 3] * w[c + 3];
    }
    lg[b][n] = d;
  }
  __syncthreads();
  if (tid < BB) {
    int b = tid;
    float m = lg[b][0];
#pragma unroll
    for (int n = 1; n < NF; ++n) m = fmaxf(m, lg[b][n]);
    float e[NF];
    float s = 0.f;
#pragma unroll
    for (int n = 0; n < NF; ++n) { e[n] = expf(lg[b][n] - m); s += e[n]; }
    float inv = 1.0f / s;
#pragma unroll
    for (int n = 0; n < NF; ++n) wsm[b][n] = e[n] * inv;
  }
  __syncthreads();
  for (int i = tid; i < BB * 49; i += 256) {
    int b = i / 49, j = i % 49;
    float acc = 0.f;
#pragma unroll
    for (int n = 0; n < NF; ++n) acc += wsm[b][n] * fbank[n * 49 + j];
    combined[b * 64 + j] = acc;
  }
}

// ---------------------------------------------------------------------------
// K3: depthwise 7x7 conv; reads bf16 xb (HALF the bytes/loads of fp32 x),
//     converts to fp32 during LDS staging -> conv inner loop unchanged.
//     kf from `combined` (block-uniform global -> SGPR taps, r15-proven).
//     TR=64, thread = 8 rows x 4 cols; fp32 compute, bf16 output.
// ---------------------------------------------------------------------------
#define TR 64
__global__ __launch_bounds__(256) void dwconv_kernel(
    const unsigned short* __restrict__ xb, const float* __restrict__ combined,
    unsigned short* __restrict__ fbp) {
  int plane = blockIdx.x;          // b*256 + c
  int rt = blockIdx.y;             // 0..1
  int b = plane >> 8;
  int r0 = rt * TR;
  int tid = threadIdx.x;

  __shared__ float xs[TR + 6][136];

  float kf[49];
  {
    const float* cb = combined + b * 64;   // uniform address -> scalar loads
#pragma unroll
    for (int i = 0; i < 49; ++i) kf[i] = cb[i];
  }

  const size_t pbase = (size_t)plane * HWSZ;
  for (int idx = tid; idx < (TR + 6) * 34; idx += 256) {
    int row = idx / 34;            // 0..69
    int seg = idx % 34;
    int r = r0 - 3 + row;
    int c = seg * 4 - 4;
    float4 v = make_float4(0.f, 0.f, 0.f, 0.f);
    if (r >= 0 && r < HH && c >= 0 && c < WW) {
      uint2 u = *(const uint2*)(xb + pbase + (size_t)r * WW + c);
      v.x = __uint_as_float(u.x << 16);
      v.y = __uint_as_float(u.x & 0xffff0000u);
      v.z = __uint_as_float(u.y << 16);
      v.w = __uint_as_float(u.y & 0xffff0000u);
    }
    *(float4*)&xs[row][seg * 4] = v;
  }
  __syncthreads();

  int cg = tid & 31;               // col group: cols 4cg..4cg+3
  int rg = tid >> 5;               // row group: rows 8rg..8rg+7 (rel to r0)
  float acc[8][4] = {};

#pragma unroll
  for (int ri = 0; ri < 14; ++ri) {          // input rows 8rg-3 .. 8rg+10
    int lrow = 8 * rg + ri;                  // LDS row index
    float xr[12];
#pragma unroll
    for (int s = 0; s < 3; ++s)
      *(float4*)&xr[4 * s] = *(const float4*)&xs[lrow][cg * 4 + 4 * s];
#pragma unroll
    for (int orr = 0; orr < 8; ++orr) {
      int dy = ri - orr;
      if (dy < 0 || dy > 6) continue;        // compile-time pruned
#pragma unroll
      for (int oc = 0; oc < 4; ++oc) {
#pragma unroll
        for (int dx = 0; dx < 7; ++dx) {
          acc[orr][oc] += xr[oc + dx + 1] * kf[dy * 7 + dx];
        }
      }
    }
  }

#pragma unroll
  for (int orr = 0; orr < 8; ++orr) {
    ushort4 sv;
    sv.x = f2bf(acc[orr][0]);
    sv.y = f2bf(acc[orr][1]);
    sv.z = f2bf(acc[orr][2]);
    sv.w = f2bf(acc[orr][3]);
    *(ushort4*)(fbp + pbase + (size_t)(r0 + 8 * rg + orr) * WW + 4 * cg) = sv;
  }
}

// ---------------------------------------------------------------------------
// K4: 1x1 conv as bf16 MFMA GEMM — in-kernel B repack, 3-buffer LDS pipeline,
//     ONE barrier per K-step, B reg-prefetch 3 deep, setprio'd MFMA (T5),
//     epilogue LDS-bounce for fully-coalesced 16B y stores.
//     Block = 256 o x 128 p, 512 thr (8 waves = 4 wm x 2 wn, each 64o x 64p).
// ---------------------------------------------------------------------------
#define SWZ(p) ((((p) >> 1) ^ ((p) >> 4)) & 3)

__global__ __launch_bounds__(512, 2) void gemm_kernel(
    const unsigned short* __restrict__ fb, const unsigned short* __restrict__ ap,
    const float* __restrict__ proj_b, unsigned short* __restrict__ yb,
    float* __restrict__ part) {
  int bid = blockIdx.x;            // bs*128 + pt
  int bs = bid >> 7;
  int pt = bid & 127;
  int p0 = pt * 128;
  int tid = threadIdx.x;
  int lane = tid & 63;
  int wave = tid >> 6;
  int wm = wave >> 1;              // 0..3 -> o 64-block
  int wn = wave & 1;               // 0..1 -> p 64-block

  // unified LDS: panels (48K A + 24K B) reused as epilogue bounce (8x64x72)
  __shared__ __align__(16) unsigned char smem[73728];
  unsigned short (*A_lds)[8192] = (unsigned short (*)[8192])smem;          // 3 bufs
  unsigned short (*B_lds)[4096] = (unsigned short (*)[4096])(smem + 49152);// 3 bufs

  // --- A staging: thread t stages MB=(t>>6) and MB=8+(t>>6)
  const unsigned short* asrc0 =
      ap + (size_t)(tid >> 6) * 4096 + (size_t)(tid & 63) * 8;
  unsigned short* adst = &A_lds[0][0] + (size_t)tid * 8;

  // --- B staging: thread t reg-loads c rows {2cp,2cp+1}, p = 4pq..4pq+3
  int cp = tid >> 5;               // 0..15
  int pq = tid & 31;               // 0..31
  const unsigned short* bsrc0 =
      fb + ((size_t)bs * CC + 2 * cp) * HWSZ + p0 + 4 * pq;

  uint2 bregs[4][2];               // [slot = kb&3][row]

#define STAGE_A(kb, buf)                                                      \
  do {                                                                        \
    gload_lds16(asrc0 + (size_t)(kb) * 512, adst + (size_t)(buf) * 8192);     \
    gload_lds16(asrc0 + 32768 + (size_t)(kb) * 512,                           \
                adst + (size_t)(buf) * 8192 + 4096);                          \
  } while (0)
#define LOAD_B(kb, slot)                                                      \
  do {                                                                        \
    const unsigned short* s_ = bsrc0 + (size_t)(kb) * 32 * HWSZ;              \
    bregs[slot][0] = *(const uint2*)s_;                                       \
    bregs[slot][1] = *(const uint2*)(s_ + HWSZ);                              \
  } while (0)
#define WRITE_B(slot, buf)                                                    \
  do {                                                                        \
    unsigned int w0_[2] = {bregs[slot][0].x, bregs[slot][0].y};               \
    unsigned int w1_[2] = {bregs[slot][1].x, bregs[slot][1].y};               \
    _Pragma("unroll")                                                         \
    for (int j_ = 0; j_ < 4; ++j_) {                                          \
      int p_ = 4 * pq + j_;                                                   \
      int cc_ = (2 * cp) ^ (SWZ(p_) << 3);                                    \
      unsigned int lo_ = (w0_[j_ >> 1] >> ((j_ & 1) * 16)) & 0xffffu;         \
      unsigned int hi_ = (w1_[j_ >> 1] >> ((j_ & 1) * 16)) & 0xffffu;         \
      *(unsigned int*)&B_lds[buf][p_ * 32 + cc_] = lo_ | (hi_ << 16);         \
    }                                                                         \
  } while (0)

  // ---- prologue: FIFO order A0,B0,A1,B1,B2 (10 vm ops)
  STAGE_A(0, 0);
  LOAD_B(0, 0);
  STAGE_A(1, 1);
  LOAD_B(1, 1);
  LOAD_B(2, 2);

  f32x4 acc[4][4];
#pragma unroll
  for (int mb = 0; mb < 4; ++mb)
#pragma unroll
    for (int nb = 0; nb < 4; ++nb) acc[mb][nb] = (f32x4){0.f, 0.f, 0.f, 0.f};

  // LDS read offsets (elements)
  int aofs[4];
#pragma unroll
  for (int mb = 0; mb < 4; ++mb) aofs[mb] = ((wm * 4 + mb) * 64 + lane) * 8;
  int bofs[4];
#pragma unroll
  for (int nb = 0; nb < 4; ++nb) {
    int pp = wn * 64 + nb * 16 + (lane & 15);
    bofs[nb] = pp * 32 + (((lane >> 4) * 8) ^ (SWZ(pp) << 3));
  }

  // retire A0+B0 (oldest 4 of 10), publish B(0)
  asm volatile("s_waitcnt vmcnt(6)" ::: "memory");
  WRITE_B(0, 0);
  asm volatile("s_waitcnt lgkmcnt(0)" ::: "memory");
  __builtin_amdgcn_s_barrier();              // panel 0 published

#pragma unroll
  for (int kb = 0; kb < 8; ++kb) {
    const int cur = kb % 3;
    const int n1 = (kb + 1) % 3;
    // 1. issue A(kb+2) into LDS buf (kb+2)%3 (released at barrier kb-1),
    //    then B(kb+3) into reg slot (kb+3)&3
    if (kb < 6) STAGE_A(kb + 2, (kb + 2) % 3);
    if (kb < 5) LOAD_B(kb + 3, (kb + 3) & 3);
    if (kb < 6) __builtin_amdgcn_sched_barrier(0);
    // 2. read fragments of panel kb (published)
    short8 af[4], bfr[4];
#pragma unroll
    for (int mb = 0; mb < 4; ++mb)
      af[mb] = *(const short8*)(&A_lds[cur][0] + aofs[mb]);
#pragma unroll
    for (int nb = 0; nb < 4; ++nb)
      bfr[nb] = *(const short8*)(&B_lds[cur][0] + bofs[nb]);
    // 3. retire A(kb+1) [LDS] + B(kb+1) [regs, issued kb-2], publish B(kb+1)
    if (kb <= 4) {
      asm volatile("s_waitcnt vmcnt(6)" ::: "memory");
      WRITE_B((kb + 1) & 3, n1);
    } else if (kb == 5) {
      asm volatile("s_waitcnt vmcnt(4)" ::: "memory");
      WRITE_B((kb + 1) & 3, n1);
    } else if (kb == 6) {
      asm volatile("s_waitcnt vmcnt(0)" ::: "memory");
      WRITE_B((kb + 1) & 3, n1);
    }
    // 4. all LDS ops (frag reads + B writes) complete
    asm volatile("s_waitcnt lgkmcnt(0)" ::: "memory");
    __builtin_amdgcn_sched_barrier(0);
    // 5. MFMA on panel kb (T5)
    __builtin_amdgcn_s_setprio(1);
#pragma unroll
    for (int mb = 0; mb < 4; ++mb)
#pragma unroll
      for (int nb = 0; nb < 4; ++nb)
        acc[mb][nb] = __builtin_amdgcn_mfma_f32_16x16x32_bf16(
            af[mb], bfr[nb], acc[mb][nb], 0, 0, 0);
    __builtin_amdgcn_s_setprio(0);
    // 6. single barrier: publishes panel kb+1, releases buf cur
    if (kb < 7) __builtin_amdgcn_s_barrier();
  }

  // all waves' panel reads done -> smem reusable as bounce
  __builtin_amdgcn_s_barrier();

  // ---- epilogue: bias, GN partials, LDS bounce, coalesced 16B y stores
  // C/D layout: col(p) = lane&15, row(o) = (lane>>4)*4 + reg
  unsigned short* yt = (unsigned short*)smem + (size_t)wave * 4608;  // 64x72
  float psum[2] = {0.f, 0.f}, psq[2] = {0.f, 0.f};
  int orl = (lane >> 4) * 4;
  int pl = lane & 15;
#pragma unroll
  for (int mb = 0; mb < 4; ++mb) {
    int gi = mb >> 1;                        // wave covers 2 GN groups (64 ch)
#pragma unroll
    for (int r = 0; r < 4; ++r) {
      int ol = mb * 16 + orl + r;
      float pb = proj_b[wm * 64 + ol];
#pragma unroll
      for (int nb = 0; nb < 4; ++nb) {
        float v = acc[mb][nb][r] + pb;
        yt[ol * 72 + pl + nb * 16] = f2bf(v);
        psum[gi] += v;
        psq[gi] += v * v;
      }
    }
  }
  // wave-private bounce: same-wave ds_write->ds_read ordered by lgkmcnt
  const size_t ybase = (size_t)bs * CC * HWSZ + p0 + wn * 64;
#pragma unroll
  for (int k = 0; k < 8; ++k) {
    int idx = k * 64 + lane;
    int ol = idx >> 3, ch = idx & 7;
    uint4 v = *(const uint4*)(yt + ol * 72 + ch * 8);
    *(uint4*)(yb + ybase + (size_t)(wm * 64 + ol) * HWSZ + ch * 8) = v;
  }

#pragma unroll
  for (int off = 32; off > 0; off >>= 1) {
#pragma unroll
    for (int k = 0; k < 2; ++k) {
      psum[k] += __shfl_down(psum[k], off, 64);
      psq[k] += __shfl_down(psq[k], off, 64);
    }
  }
  if (lane == 0) {
#pragma unroll
    for (int k = 0; k < 2; ++k) {
      int bg = bs * 8 + wm * 2 + k;
      part[(size_t)bg * 256 + pt * 2 + wn] = psum[k];
      part[32768 + (size_t)bg * 256 + pt * 2 + wn] = psq[k];
    }
  }
#undef STAGE_A
#undef LOAD_B
#undef WRITE_B
}

// ---------------------------------------------------------------------------
// K5: GroupNorm affine + exact GELU + residual, with IN-KERNEL stats reduce.
//     Reads bf16 y + fp32 x, writes fp32 out (overwrites xb region).
// ---------------------------------------------------------------------------
__global__ __launch_bounds__(256) void out_kernel(
    const float* __restrict__ x, const unsigned short* __restrict__ yb,
    const float* __restrict__ part, const float* __restrict__ gamma,
    const float* __restrict__ beta, float* __restrict__ out) {
  int plane = blockIdx.x;
  int b = plane >> 8, c = plane & 255, g = c >> 5;
  int bg = b * 8 + g;
  int t = threadIdx.x;

  // reduce this group's 256 partials (all threads participate)
  float s = part[(size_t)bg * 256 + t];
  float q = part[32768 + (size_t)bg * 256 + t];
#pragma unroll
  for (int off = 32; off > 0; off >>= 1) {
    s += __shfl_down(s, off, 64);
    q += __shfl_down(q, off, 64);
  }
  __shared__ float ls[8];
  if ((t & 63) == 0) { ls[t >> 6] = s; ls[4 + (t >> 6)] = q; }
  __syncthreads();
  float tsum = ls[0] + ls[1] + ls[2] + ls[3];
  float tsq = ls[4] + ls[5] + ls[6] + ls[7];

  const float inv_n = 1.0f / (32.0f * (float)HWSZ);
  float mean = tsum * inv_n;
  float var = tsq * inv_n - mean * mean;
  float rstd = rsqrtf(var + EPSV);
  float scale = gamma[c] * rstd;
  float shift = beta[c] - mean * scale;

  const size_t base = (size_t)plane * HWSZ;
  for (int i = t; i < HWSZ / 8; i += 256) {
    uint4 yv = *(const uint4*)(yb + base + 8 * (size_t)i);
    float4 x0 = *(const float4*)(x + base + 8 * (size_t)i);
    float4 x1 = *(const float4*)(x + base + 8 * (size_t)i + 4);
    unsigned int yw[4] = {yv.x, yv.y, yv.z, yv.w};
    float r[8];
    float xr[8] = {x0.x, x0.y, x0.z, x0.w, x1.x, x1.y, x1.z, x1.w};
#pragma unroll
    for (int k = 0; k < 8; ++k) {
      unsigned int h = (yw[k >> 1] >> ((k & 1) * 16)) & 0xffffu;
      float tv = bf2f(h) * scale + shift;
      float ge = 0.5f * tv * (1.0f + erff(tv * 0.70710678118654752f));
      r[k] = ge + xr[k];
    }
    *(float4*)(out + base + 8 * (size_t)i) = make_float4(r[0], r[1], r[2], r[3]);
    *(float4*)(out + base + 8 * (size_t)i + 4) = make_float4(r[4], r[5], r[6], r[7]);
  }
}

// ---------------------------------------------------------------------------
extern "C" void kernel_launch(void* const* d_in, const int* in_sizes, int n_in,
                              void* d_out, int out_size, void* d_ws, size_t ws_size,
                              hipStream_t stream) {
  const float* x      = (const float*)d_in[0];
  const float* fbank  = (const float*)d_in[1];   // [NF,1,7,7]
  const float* sel_w  = (const float*)d_in[2];   // [NF,C]
  const float* sel_b  = (const float*)d_in[3];   // [NF]
  const float* proj_w = (const float*)d_in[4];   // [C,C,1,1]
  const float* proj_b = (const float*)d_in[5];   // [C]
  const float* gamma  = (const float*)d_in[6];   // [C]
  const float* beta   = (const float*)d_in[7];   // [C]
  float* out = (float*)d_out;

  // ws layout: fb bf16 [B*C*HW] | yb bf16 [B*C*HW] | ap bf16 [65536]
  //            | pooled | combined | part[65536]
  // xb (bf16 copy of x, 134 MB) lives in d_out's first half — dead by the
  // time out_kernel overwrites it.
  unsigned short* fb  = (unsigned short*)d_ws;
  unsigned short* yb  = fb + (size_t)BB * CC * HWSZ;
  unsigned short* apk = yb + (size_t)BB * CC * HWSZ;
  float* pooled   = (float*)(apk + 65536);
  float* combined = pooled + BB * CC;
  float* part     = combined + BB * 64;
  unsigned short* xb = (unsigned short*)d_out;

  hipLaunchKernelGGL(pool_pack_kernel, dim3(BB * CC + 256), dim3(256), 0, stream,
                     x, proj_w, pooled, apk, xb);
  hipLaunchKernelGGL(selector_kernel, dim3(1), dim3(256), 0, stream,
                     pooled, sel_w, sel_b, fbank, combined);
  hipLaunchKernelGGL(dwconv_kernel, dim3(BB * CC, HH / TR), dim3(256), 0, stream,
                     xb, combined, fb);
  hipLaunchKernelGGL(gemm_kernel, dim3(BB * 128), dim3(512), 0, stream,
                     fb, apk, proj_b, yb, part);
  hipLaunchKernelGGL(out_kernel, dim3(BB * CC), dim3(256), 0, stream,
                     x, yb, part, gamma, beta, out);
}

// Round 18
// 410.955 us; speedup vs baseline: 1.1138x; 1.0470x over previous
//
#include <hip/hip_runtime.h>
#include <math.h>

// Problem constants
#define BB 16
#define CC 256
#define HH 128
#define WW 128
#define HWSZ 16384        // H*W
#define NF 8
#define EPSV 1e-5f

typedef __attribute__((ext_vector_type(8))) short short8;   // 8 bf16 = 4 VGPRs
typedef __attribute__((ext_vector_type(4))) float f32x4;

static __device__ __forceinline__ unsigned short f2bf(float f) {
  unsigned int u = __float_as_uint(f);
  u += 0x7fffu + ((u >> 16) & 1u);       // round-to-nearest-even
  return (unsigned short)(u >> 16);
}

static __device__ __forceinline__ float bf2f(unsigned int h) {
  return __uint_as_float(h << 16);
}

static __device__ __forceinline__ void gload_lds16(const unsigned short* g,
                                                   unsigned short* l) {
  __builtin_amdgcn_global_load_lds(
      (const __attribute__((address_space(1))) void*)(size_t)g,
      (__attribute__((address_space(3))) void*)(unsigned)(size_t)l, 16, 0, 0);
}

// ---------------------------------------------------------------------------
// K1: fused  (a) pooled[b,c] = mean over HW   (blocks 0..4095)
//            (b) pack proj_w -> bf16 A-frag order (blocks 4096..4351)
//     (r15-proven form, no xb cast)
// ---------------------------------------------------------------------------
__global__ __launch_bounds__(256) void pool_pack_kernel(
    const float* __restrict__ x, const float* __restrict__ pw,
    float* __restrict__ pooled, unsigned short* __restrict__ ap) {
  int blk = blockIdx.x;
  int tid = threadIdx.x;
  if (blk >= BB * CC) {            // pack_a part
    int idx = (blk - BB * CC) * 256 + tid;      // 0..65535
    int e = idx & 7;
    int lane = (idx >> 3) & 63;
    int kb = (idx >> 9) & 7;
    int mb = idx >> 12;
    int o = mb * 16 + (lane & 15);
    int c = kb * 32 + (lane >> 4) * 8 + e;
    ap[idx] = f2bf(pw[o * 256 + c]);
    return;
  }
  // pool part
  const float4* xp = (const float4*)(x + (size_t)blk * HWSZ);
  float s = 0.f;
#pragma unroll
  for (int i = 0; i < 16; ++i) {
    float4 v = xp[tid + i * 256];
    s += v.x + v.y + v.z + v.w;
  }
#pragma unroll
  for (int off = 32; off > 0; off >>= 1) s += __shfl_down(s, off, 64);
  __shared__ float ls[4];
  if ((tid & 63) == 0) ls[tid >> 6] = s;
  __syncthreads();
  if (tid == 0) pooled[blk] = (ls[0] + ls[1] + ls[2] + ls[3]) * (1.0f / 16384.0f);
}

// ---------------------------------------------------------------------------
// K2: selector: GAP -> linear -> softmax -> mix filter bank. (r15-proven)
// ---------------------------------------------------------------------------
__global__ __launch_bounds__(256) void selector_kernel(
    const float* __restrict__ pooled, const float* __restrict__ sel_w,
    const float* __restrict__ sel_b, const float* __restrict__ fbank,
    float* __restrict__ combined) {
  int tid = threadIdx.x;
  __shared__ float lg[BB][NF];
  __shared__ float wsm[BB][NF];
  if (tid < BB * NF) {
    int b = tid >> 3, n = tid & 7;
    const float* p = pooled + b * CC;
    const float* w = sel_w + n * CC;
    float d = sel_b[n];
    for (int c = 0; c < CC; c += 4) {
      d += p[c] * w[c] + p[c + 1] * w[c + 1] + p[c + 2] * w[c + 2] + p[c + 3] * w[c + 3];
    }
    lg[b][n] = d;
  }
  __syncthreads();
  if (tid < BB) {
    int b = tid;
    float m = lg[b][0];
#pragma unroll
    for (int n = 1; n < NF; ++n) m = fmaxf(m, lg[b][n]);
    float e[NF];
    float s = 0.f;
#pragma unroll
    for (int n = 0; n < NF; ++n) { e[n] = expf(lg[b][n] - m); s += e[n]; }
    float inv = 1.0f / s;
#pragma unroll
    for (int n = 0; n < NF; ++n) wsm[b][n] = e[n] * inv;
  }
  __syncthreads();
  for (int i = tid; i < BB * 49; i += 256) {
    int b = i / 49, j = i % 49;
    float acc = 0.f;
#pragma unroll
    for (int n = 0; n < NF; ++n) acc += wsm[b][n] * fbank[n * 49 + j];
    combined[b * 64 + j] = acc;
  }
}

// ---------------------------------------------------------------------------
// K3: depthwise 7x7 conv (r15-proven: fp32 x, TR=64, combined-pointer kf).
// ---------------------------------------------------------------------------
#define TR 64
__global__ __launch_bounds__(256) void dwconv_kernel(
    const float* __restrict__ x, const float* __restrict__ combined,
    unsigned short* __restrict__ fbp) {
  int plane = blockIdx.x;          // b*256 + c
  int rt = blockIdx.y;             // 0..1
  int b = plane >> 8;
  int r0 = rt * TR;
  int tid = threadIdx.x;

  __shared__ float xs[TR + 6][136];

  float kf[49];
  {
    const float* cb = combined + b * 64;   // uniform address -> scalar loads
#pragma unroll
    for (int i = 0; i < 49; ++i) kf[i] = cb[i];
  }

  const size_t pbase = (size_t)plane * HWSZ;
  for (int idx = tid; idx < (TR + 6) * 34; idx += 256) {
    int row = idx / 34;            // 0..69
    int seg = idx % 34;
    int r = r0 - 3 + row;
    int c = seg * 4 - 4;
    float4 v = make_float4(0.f, 0.f, 0.f, 0.f);
    if (r >= 0 && r < HH && c >= 0 && c < WW) {
      v = *(const float4*)(x + pbase + (size_t)r * WW + c);
    }
    *(float4*)&xs[row][seg * 4] = v;
  }
  __syncthreads();

  int cg = tid & 31;               // col group: cols 4cg..4cg+3
  int rg = tid >> 5;               // row group: rows 8rg..8rg+7 (rel to r0)
  float acc[8][4] = {};

#pragma unroll
  for (int ri = 0; ri < 14; ++ri) {          // input rows 8rg-3 .. 8rg+10
    int lrow = 8 * rg + ri;                  // LDS row index
    float xr[12];
#pragma unroll
    for (int s = 0; s < 3; ++s)
      *(float4*)&xr[4 * s] = *(const float4*)&xs[lrow][cg * 4 + 4 * s];
#pragma unroll
    for (int orr = 0; orr < 8; ++orr) {
      int dy = ri - orr;
      if (dy < 0 || dy > 6) continue;        // compile-time pruned
#pragma unroll
      for (int oc = 0; oc < 4; ++oc) {
#pragma unroll
        for (int dx = 0; dx < 7; ++dx) {
          acc[orr][oc] += xr[oc + dx + 1] * kf[dy * 7 + dx];
        }
      }
    }
  }

#pragma unroll
  for (int orr = 0; orr < 8; ++orr) {
    ushort4 sv;
    sv.x = f2bf(acc[orr][0]);
    sv.y = f2bf(acc[orr][1]);
    sv.z = f2bf(acc[orr][2]);
    sv.w = f2bf(acc[orr][3]);
    *(ushort4*)(fbp + pbase + (size_t)(r0 + 8 * rg + orr) * WW + 4 * cg) = sv;
  }
}

// ---------------------------------------------------------------------------
// K4: 1x1 conv as bf16 MFMA GEMM — in-kernel B repack, 3-buffer LDS pipeline,
//     ONE barrier per K-step, B reg-prefetch 3 deep, setprio'd MFMA (T5),
//     epilogue LDS-bounce for fully-coalesced 16B y stores (the ONE change
//     vs the 406-µs r15 baseline — isolated A/B).
//     Block = 256 o x 128 p, 512 thr (8 waves = 4 wm x 2 wn, each 64o x 64p).
// ---------------------------------------------------------------------------
#define SWZ(p) ((((p) >> 1) ^ ((p) >> 4)) & 3)

__global__ __launch_bounds__(512, 2) void gemm_kernel(
    const unsigned short* __restrict__ fb, const unsigned short* __restrict__ ap,
    const float* __restrict__ proj_b, unsigned short* __restrict__ yb,
    float* __restrict__ part) {
  int bid = blockIdx.x;            // bs*128 + pt
  int bs = bid >> 7;
  int pt = bid & 127;
  int p0 = pt * 128;
  int tid = threadIdx.x;
  int lane = tid & 63;
  int wave = tid >> 6;
  int wm = wave >> 1;              // 0..3 -> o 64-block
  int wn = wave & 1;               // 0..1 -> p 64-block

  // unified LDS: panels (48K A + 24K B) reused as epilogue bounce (8x64x72)
  __shared__ __align__(16) unsigned char smem[73728];
  unsigned short (*A_lds)[8192] = (unsigned short (*)[8192])smem;          // 3 bufs
  unsigned short (*B_lds)[4096] = (unsigned short (*)[4096])(smem + 49152);// 3 bufs

  // --- A staging: thread t stages MB=(t>>6) and MB=8+(t>>6)
  const unsigned short* asrc0 =
      ap + (size_t)(tid >> 6) * 4096 + (size_t)(tid & 63) * 8;
  unsigned short* adst = &A_lds[0][0] + (size_t)tid * 8;

  // --- B staging: thread t reg-loads c rows {2cp,2cp+1}, p = 4pq..4pq+3
  int cp = tid >> 5;               // 0..15
  int pq = tid & 31;               // 0..31
  const unsigned short* bsrc0 =
      fb + ((size_t)bs * CC + 2 * cp) * HWSZ + p0 + 4 * pq;

  uint2 bregs[4][2];               // [slot = kb&3][row]

#define STAGE_A(kb, buf)                                                      \
  do {                                                                        \
    gload_lds16(asrc0 + (size_t)(kb) * 512, adst + (size_t)(buf) * 8192);     \
    gload_lds16(asrc0 + 32768 + (size_t)(kb) * 512,                           \
                adst + (size_t)(buf) * 8192 + 4096);                          \
  } while (0)
#define LOAD_B(kb, slot)                                                      \
  do {                                                                        \
    const unsigned short* s_ = bsrc0 + (size_t)(kb) * 32 * HWSZ;              \
    bregs[slot][0] = *(const uint2*)s_;                                       \
    bregs[slot][1] = *(const uint2*)(s_ + HWSZ);                              \
  } while (0)
#define WRITE_B(slot, buf)                                                    \
  do {                                                                        \
    unsigned int w0_[2] = {bregs[slot][0].x, bregs[slot][0].y};               \
    unsigned int w1_[2] = {bregs[slot][1].x, bregs[slot][1].y};               \
    _Pragma("unroll")                                                         \
    for (int j_ = 0; j_ < 4; ++j_) {                                          \
      int p_ = 4 * pq + j_;                                                   \
      int cc_ = (2 * cp) ^ (SWZ(p_) << 3);                                    \
      unsigned int lo_ = (w0_[j_ >> 1] >> ((j_ & 1) * 16)) & 0xffffu;         \
      unsigned int hi_ = (w1_[j_ >> 1] >> ((j_ & 1) * 16)) & 0xffffu;         \
      *(unsigned int*)&B_lds[buf][p_ * 32 + cc_] = lo_ | (hi_ << 16);         \
    }                                                                         \
  } while (0)

  // ---- prologue: FIFO order A0,B0,A1,B1,B2 (10 vm ops)
  STAGE_A(0, 0);
  LOAD_B(0, 0);
  STAGE_A(1, 1);
  LOAD_B(1, 1);
  LOAD_B(2, 2);

  f32x4 acc[4][4];
#pragma unroll
  for (int mb = 0; mb < 4; ++mb)
#pragma unroll
    for (int nb = 0; nb < 4; ++nb) acc[mb][nb] = (f32x4){0.f, 0.f, 0.f, 0.f};

  // LDS read offsets (elements)
  int aofs[4];
#pragma unroll
  for (int mb = 0; mb < 4; ++mb) aofs[mb] = ((wm * 4 + mb) * 64 + lane) * 8;
  int bofs[4];
#pragma unroll
  for (int nb = 0; nb < 4; ++nb) {
    int pp = wn * 64 + nb * 16 + (lane & 15);
    bofs[nb] = pp * 32 + (((lane >> 4) * 8) ^ (SWZ(pp) << 3));
  }

  // retire A0+B0 (oldest 4 of 10), publish B(0)
  asm volatile("s_waitcnt vmcnt(6)" ::: "memory");
  WRITE_B(0, 0);
  asm volatile("s_waitcnt lgkmcnt(0)" ::: "memory");
  __builtin_amdgcn_s_barrier();              // panel 0 published

#pragma unroll
  for (int kb = 0; kb < 8; ++kb) {
    const int cur = kb % 3;
    const int n1 = (kb + 1) % 3;
    // 1. issue A(kb+2) into LDS buf (kb+2)%3 (released at barrier kb-1),
    //    then B(kb+3) into reg slot (kb+3)&3
    if (kb < 6) STAGE_A(kb + 2, (kb + 2) % 3);
    if (kb < 5) LOAD_B(kb + 3, (kb + 3) & 3);
    if (kb < 6) __builtin_amdgcn_sched_barrier(0);
    // 2. read fragments of panel kb (published)
    short8 af[4], bfr[4];
#pragma unroll
    for (int mb = 0; mb < 4; ++mb)
      af[mb] = *(const short8*)(&A_lds[cur][0] + aofs[mb]);
#pragma unroll
    for (int nb = 0; nb < 4; ++nb)
      bfr[nb] = *(const short8*)(&B_lds[cur][0] + bofs[nb]);
    // 3. retire A(kb+1) [LDS] + B(kb+1) [regs, issued kb-2], publish B(kb+1)
    if (kb <= 4) {
      asm volatile("s_waitcnt vmcnt(6)" ::: "memory");
      WRITE_B((kb + 1) & 3, n1);
    } else if (kb == 5) {
      asm volatile("s_waitcnt vmcnt(4)" ::: "memory");
      WRITE_B((kb + 1) & 3, n1);
    } else if (kb == 6) {
      asm volatile("s_waitcnt vmcnt(0)" ::: "memory");
      WRITE_B((kb + 1) & 3, n1);
    }
    // 4. all LDS ops (frag reads + B writes) complete
    asm volatile("s_waitcnt lgkmcnt(0)" ::: "memory");
    __builtin_amdgcn_sched_barrier(0);
    // 5. MFMA on panel kb (T5)
    __builtin_amdgcn_s_setprio(1);
#pragma unroll
    for (int mb = 0; mb < 4; ++mb)
#pragma unroll
      for (int nb = 0; nb < 4; ++nb)
        acc[mb][nb] = __builtin_amdgcn_mfma_f32_16x16x32_bf16(
            af[mb], bfr[nb], acc[mb][nb], 0, 0, 0);
    __builtin_amdgcn_s_setprio(0);
    // 6. single barrier: publishes panel kb+1, releases buf cur
    if (kb < 7) __builtin_amdgcn_s_barrier();
  }

  // all waves' panel reads done -> smem reusable as bounce
  __builtin_amdgcn_s_barrier();

  // ---- epilogue: bias, GN partials, LDS bounce, coalesced 16B y stores
  // C/D layout: col(p) = lane&15, row(o) = (lane>>4)*4 + reg
  unsigned short* yt = (unsigned short*)smem + (size_t)wave * 4608;  // 64x72
  float psum[2] = {0.f, 0.f}, psq[2] = {0.f, 0.f};
  int orl = (lane >> 4) * 4;
  int pl = lane & 15;
#pragma unroll
  for (int mb = 0; mb < 4; ++mb) {
    int gi = mb >> 1;                        // wave covers 2 GN groups (64 ch)
#pragma unroll
    for (int r = 0; r < 4; ++r) {
      int ol = mb * 16 + orl + r;
      float pb = proj_b[wm * 64 + ol];
#pragma unroll
      for (int nb = 0; nb < 4; ++nb) {
        float v = acc[mb][nb][r] + pb;
        yt[ol * 72 + pl + nb * 16] = f2bf(v);
        psum[gi] += v;
        psq[gi] += v * v;
      }
    }
  }
  // wave-private bounce: same-wave ds_write->ds_read ordered by lgkmcnt
  const size_t ybase = (size_t)bs * CC * HWSZ + p0 + wn * 64;
#pragma unroll
  for (int k = 0; k < 8; ++k) {
    int idx = k * 64 + lane;
    int ol = idx >> 3, ch = idx & 7;
    uint4 v = *(const uint4*)(yt + ol * 72 + ch * 8);
    *(uint4*)(yb + ybase + (size_t)(wm * 64 + ol) * HWSZ + ch * 8) = v;
  }

#pragma unroll
  for (int off = 32; off > 0; off >>= 1) {
#pragma unroll
    for (int k = 0; k < 2; ++k) {
      psum[k] += __shfl_down(psum[k], off, 64);
      psq[k] += __shfl_down(psq[k], off, 64);
    }
  }
  if (lane == 0) {
#pragma unroll
    for (int k = 0; k < 2; ++k) {
      int bg = bs * 8 + wm * 2 + k;
      part[(size_t)bg * 256 + pt * 2 + wn] = psum[k];
      part[32768 + (size_t)bg * 256 + pt * 2 + wn] = psq[k];
    }
  }
#undef STAGE_A
#undef LOAD_B
#undef WRITE_B
}

// ---------------------------------------------------------------------------
// K5: GroupNorm affine + exact GELU + residual, with IN-KERNEL stats reduce.
//     Reads bf16 y + fp32 x, writes fp32 out.
// ---------------------------------------------------------------------------
__global__ __launch_bounds__(256) void out_kernel(
    const float* __restrict__ x, const unsigned short* __restrict__ yb,
    const float* __restrict__ part, const float* __restrict__ gamma,
    const float* __restrict__ beta, float* __restrict__ out) {
  int plane = blockIdx.x;
  int b = plane >> 8, c = plane & 255, g = c >> 5;
  int bg = b * 8 + g;
  int t = threadIdx.x;

  // reduce this group's 256 partials (all threads participate)
  float s = part[(size_t)bg * 256 + t];
  float q = part[32768 + (size_t)bg * 256 + t];
#pragma unroll
  for (int off = 32; off > 0; off >>= 1) {
    s += __shfl_down(s, off, 64);
    q += __shfl_down(q, off, 64);
  }
  __shared__ float ls[8];
  if ((t & 63) == 0) { ls[t >> 6] = s; ls[4 + (t >> 6)] = q; }
  __syncthreads();
  float tsum = ls[0] + ls[1] + ls[2] + ls[3];
  float tsq = ls[4] + ls[5] + ls[6] + ls[7];

  const float inv_n = 1.0f / (32.0f * (float)HWSZ);
  float mean = tsum * inv_n;
  float var = tsq * inv_n - mean * mean;
  float rstd = rsqrtf(var + EPSV);
  float scale = gamma[c] * rstd;
  float shift = beta[c] - mean * scale;

  const size_t base = (size_t)plane * HWSZ;
  for (int i = t; i < HWSZ / 8; i += 256) {
    uint4 yv = *(const uint4*)(yb + base + 8 * (size_t)i);
    float4 x0 = *(const float4*)(x + base + 8 * (size_t)i);
    float4 x1 = *(const float4*)(x + base + 8 * (size_t)i + 4);
    unsigned int yw[4] = {yv.x, yv.y, yv.z, yv.w};
    float r[8];
    float xr[8] = {x0.x, x0.y, x0.z, x0.w, x1.x, x1.y, x1.z, x1.w};
#pragma unroll
    for (int k = 0; k < 8; ++k) {
      unsigned int h = (yw[k >> 1] >> ((k & 1) * 16)) & 0xffffu;
      float tv = bf2f(h) * scale + shift;
      float ge = 0.5f * tv * (1.0f + erff(tv * 0.70710678118654752f));
      r[k] = ge + xr[k];
    }
    *(float4*)(out + base + 8 * (size_t)i) = make_float4(r[0], r[1], r[2], r[3]);
    *(float4*)(out + base + 8 * (size_t)i + 4) = make_float4(r[4], r[5], r[6], r[7]);
  }
}

// ---------------------------------------------------------------------------
extern "C" void kernel_launch(void* const* d_in, const int* in_sizes, int n_in,
                              void* d_out, int out_size, void* d_ws, size_t ws_size,
                              hipStream_t stream) {
  const float* x      = (const float*)d_in[0];
  const float* fbank  = (const float*)d_in[1];   // [NF,1,7,7]
  const float* sel_w  = (const float*)d_in[2];   // [NF,C]
  const float* sel_b  = (const float*)d_in[3];   // [NF]
  const float* proj_w = (const float*)d_in[4];   // [C,C,1,1]
  const float* proj_b = (const float*)d_in[5];   // [C]
  const float* gamma  = (const float*)d_in[6];   // [C]
  const float* beta   = (const float*)d_in[7];   // [C]
  float* out = (float*)d_out;

  // ws layout: fb bf16 [B*C*HW] | yb bf16 [B*C*HW] | ap bf16 [65536]
  //            | pooled | combined | part[65536]
  unsigned short* fb  = (unsigned short*)d_ws;
  unsigned short* yb  = fb + (size_t)BB * CC * HWSZ;
  unsigned short* apk = yb + (size_t)BB * CC * HWSZ;
  float* pooled   = (float*)(apk + 65536);
  float* combined = pooled + BB * CC;
  float* part     = combined + BB * 64;

  hipLaunchKernelGGL(pool_pack_kernel, dim3(BB * CC + 256), dim3(256), 0, stream,
                     x, proj_w, pooled, apk);
  hipLaunchKernelGGL(selector_kernel, dim3(1), dim3(256), 0, stream,
                     pooled, sel_w, sel_b, fbank, combined);
  hipLaunchKernelGGL(dwconv_kernel, dim3(BB * CC, HH / TR), dim3(256), 0, stream,
                     x, combined, fb);
  hipLaunchKernelGGL(gemm_kernel, dim3(BB * 128), dim3(512), 0, stream,
                     fb, apk, proj_b, yb, part);
  hipLaunchKernelGGL(out_kernel, dim3(BB * CC), dim3(256), 0, stream,
                     x, yb, part, gamma, beta, out);
}

// Round 19
// 403.860 us; speedup vs baseline: 1.1334x; 1.0176x over previous
//
#include <hip/hip_runtime.h>
#include <math.h>

// Problem constants
#define BB 16
#define CC 256
#define HH 128
#define WW 128
#define HWSZ 16384        // H*W
#define NF 8
#define EPSV 1e-5f

typedef __attribute__((ext_vector_type(8))) short short8;   // 8 bf16 = 4 VGPRs
typedef __attribute__((ext_vector_type(4))) float f32x4;

static __device__ __forceinline__ unsigned short f2bf(float f) {
  unsigned int u = __float_as_uint(f);
  u += 0x7fffu + ((u >> 16) & 1u);       // round-to-nearest-even
  return (unsigned short)(u >> 16);
}

static __device__ __forceinline__ float bf2f(unsigned int h) {
  return __uint_as_float(h << 16);
}

static __device__ __forceinline__ void gload_lds16(const unsigned short* g,
                                                   unsigned short* l) {
  __builtin_amdgcn_global_load_lds(
      (const __attribute__((address_space(1))) void*)(size_t)g,
      (__attribute__((address_space(3))) void*)(unsigned)(size_t)l, 16, 0, 0);
}

// ---------------------------------------------------------------------------
// K1: fused  (a) pooled[b,c] = mean over HW   (blocks 0..4095)
//            (b) pack proj_w -> bf16 A-frag order (blocks 4096..4351)
// ---------------------------------------------------------------------------
__global__ __launch_bounds__(256) void pool_pack_kernel(
    const float* __restrict__ x, const float* __restrict__ pw,
    float* __restrict__ pooled, unsigned short* __restrict__ ap) {
  int blk = blockIdx.x;
  int tid = threadIdx.x;
  if (blk >= BB * CC) {            // pack_a part
    int idx = (blk - BB * CC) * 256 + tid;      // 0..65535
    int e = idx & 7;
    int lane = (idx >> 3) & 63;
    int kb = (idx >> 9) & 7;
    int mb = idx >> 12;
    int o = mb * 16 + (lane & 15);
    int c = kb * 32 + (lane >> 4) * 8 + e;
    ap[idx] = f2bf(pw[o * 256 + c]);
    return;
  }
  // pool part
  const float4* xp = (const float4*)(x + (size_t)blk * HWSZ);
  float s = 0.f;
#pragma unroll
  for (int i = 0; i < 16; ++i) {
    float4 v = xp[tid + i * 256];
    s += v.x + v.y + v.z + v.w;
  }
#pragma unroll
  for (int off = 32; off > 0; off >>= 1) s += __shfl_down(s, off, 64);
  __shared__ float ls[4];
  if ((tid & 63) == 0) ls[tid >> 6] = s;
  __syncthreads();
  if (tid == 0) pooled[blk] = (ls[0] + ls[1] + ls[2] + ls[3]) * (1.0f / 16384.0f);
}

// ---------------------------------------------------------------------------
// K2: selector: GAP -> linear -> softmax -> mix filter bank.
// ---------------------------------------------------------------------------
__global__ __launch_bounds__(256) void selector_kernel(
    const float* __restrict__ pooled, const float* __restrict__ sel_w,
    const float* __restrict__ sel_b, const float* __restrict__ fbank,
    float* __restrict__ combined) {
  int tid = threadIdx.x;
  __shared__ float lg[BB][NF];
  __shared__ float wsm[BB][NF];
  if (tid < BB * NF) {
    int b = tid >> 3, n = tid & 7;
    const float* p = pooled + b * CC;
    const float* w = sel_w + n * CC;
    float d = sel_b[n];
    for (int c = 0; c < CC; c += 4) {
      d += p[c] * w[c] + p[c + 1] * w[c + 1] + p[c + 2] * w[c + 2] + p[c + 3] * w[c + 3];
    }
    lg[b][n] = d;
  }
  __syncthreads();
  if (tid < BB) {
    int b = tid;
    float m = lg[b][0];
#pragma unroll
    for (int n = 1; n < NF; ++n) m = fmaxf(m, lg[b][n]);
    float e[NF];
    float s = 0.f;
#pragma unroll
    for (int n = 0; n < NF; ++n) { e[n] = expf(lg[b][n] - m); s += e[n]; }
    float inv = 1.0f / s;
#pragma unroll
    for (int n = 0; n < NF; ++n) wsm[b][n] = e[n] * inv;
  }
  __syncthreads();
  for (int i = tid; i < BB * 49; i += 256) {
    int b = i / 49, j = i % 49;
    float acc = 0.f;
#pragma unroll
    for (int n = 0; n < NF; ++n) acc += wsm[b][n] * fbank[n * 49 + j];
    combined[b * 64 + j] = acc;
  }
}

// ---------------------------------------------------------------------------
// K3: depthwise 7x7 conv, per-sample filter; fp32 compute, bf16 output.
//     TR=64, thread = 8 rows x 4 cols; kf via block-uniform pointer (SGPR).
// ---------------------------------------------------------------------------
#define TR 64
__global__ __launch_bounds__(256) void dwconv_kernel(
    const float* __restrict__ x, const float* __restrict__ combined,
    unsigned short* __restrict__ fbp) {
  int plane = blockIdx.x;          // b*256 + c
  int rt = blockIdx.y;             // 0..1
  int b = plane >> 8;
  int r0 = rt * TR;
  int tid = threadIdx.x;

  __shared__ float xs[TR + 6][136];

  float kf[49];
  {
    const float* cb = combined + b * 64;   // uniform address -> scalar loads
#pragma unroll
    for (int i = 0; i < 49; ++i) kf[i] = cb[i];
  }

  const size_t pbase = (size_t)plane * HWSZ;
  for (int idx = tid; idx < (TR + 6) * 34; idx += 256) {
    int row = idx / 34;            // 0..69
    int seg = idx % 34;
    int r = r0 - 3 + row;
    int c = seg * 4 - 4;
    float4 v = make_float4(0.f, 0.f, 0.f, 0.f);
    if (r >= 0 && r < HH && c >= 0 && c < WW) {
      v = *(const float4*)(x + pbase + (size_t)r * WW + c);
    }
    *(float4*)&xs[row][seg * 4] = v;
  }
  __syncthreads();

  int cg = tid & 31;               // col group: cols 4cg..4cg+3
  int rg = tid >> 5;               // row group: rows 8rg..8rg+7 (rel to r0)
  float acc[8][4] = {};

#pragma unroll
  for (int ri = 0; ri < 14; ++ri) {          // input rows 8rg-3 .. 8rg+10
    int lrow = 8 * rg + ri;                  // LDS row index
    float xr[12];
#pragma unroll
    for (int s = 0; s < 3; ++s)
      *(float4*)&xr[4 * s] = *(const float4*)&xs[lrow][cg * 4 + 4 * s];
#pragma unroll
    for (int orr = 0; orr < 8; ++orr) {
      int dy = ri - orr;
      if (dy < 0 || dy > 6) continue;        // compile-time pruned
#pragma unroll
      for (int oc = 0; oc < 4; ++oc) {
#pragma unroll
        for (int dx = 0; dx < 7; ++dx) {
          acc[orr][oc] += xr[oc + dx + 1] * kf[dy * 7 + dx];
        }
      }
    }
  }

#pragma unroll
  for (int orr = 0; orr < 8; ++orr) {
    ushort4 sv;
    sv.x = f2bf(acc[orr][0]);
    sv.y = f2bf(acc[orr][1]);
    sv.z = f2bf(acc[orr][2]);
    sv.w = f2bf(acc[orr][3]);
    *(ushort4*)(fbp + pbase + (size_t)(r0 + 8 * rg + orr) * WW + 4 * cg) = sv;
  }
}

// ---------------------------------------------------------------------------
// K4: 1x1 conv as bf16 MFMA GEMM — in-kernel B repack, 3-buffer LDS pipeline,
//     ONE barrier per K-step, B reg-prefetch 3 deep, setprio'd MFMA (T5).
//     Direct (scattered) y-stores — the r15-proven 406-µs configuration;
//     the LDS-bounce variant A/B'd neutral-to-negative in r18.
//     Block = 256 o x 128 p, 512 thr (8 waves = 4 wm x 2 wn, each 64o x 64p).
// ---------------------------------------------------------------------------
#define SWZ(p) ((((p) >> 1) ^ ((p) >> 4)) & 3)

__global__ __launch_bounds__(512, 2) void gemm_kernel(
    const unsigned short* __restrict__ fb, const unsigned short* __restrict__ ap,
    const float* __restrict__ proj_b, unsigned short* __restrict__ yb,
    float* __restrict__ part) {
  int bid = blockIdx.x;            // bs*128 + pt
  int bs = bid >> 7;
  int pt = bid & 127;
  int p0 = pt * 128;
  int tid = threadIdx.x;
  int lane = tid & 63;
  int wave = tid >> 6;
  int wm = wave >> 1;              // 0..3 -> o 64-block
  int wn = wave & 1;               // 0..1 -> p 64-block

  __shared__ __align__(16) unsigned short A_lds[3][8192];  // 3 x 16 KB
  __shared__ __align__(16) unsigned short B_lds[3][4096];  // 3 x 8 KB

  // --- A staging: thread t stages MB=(t>>6) and MB=8+(t>>6)
  const unsigned short* asrc0 =
      ap + (size_t)(tid >> 6) * 4096 + (size_t)(tid & 63) * 8;
  unsigned short* adst = &A_lds[0][0] + (size_t)tid * 8;

  // --- B staging: thread t reg-loads c rows {2cp,2cp+1}, p = 4pq..4pq+3
  int cp = tid >> 5;               // 0..15
  int pq = tid & 31;               // 0..31
  const unsigned short* bsrc0 =
      fb + ((size_t)bs * CC + 2 * cp) * HWSZ + p0 + 4 * pq;

  uint2 bregs[4][2];               // [slot = kb&3][row]

#define STAGE_A(kb, buf)                                                      \
  do {                                                                        \
    gload_lds16(asrc0 + (size_t)(kb) * 512, adst + (size_t)(buf) * 8192);     \
    gload_lds16(asrc0 + 32768 + (size_t)(kb) * 512,                           \
                adst + (size_t)(buf) * 8192 + 4096);                          \
  } while (0)
#define LOAD_B(kb, slot)                                                      \
  do {                                                                        \
    const unsigned short* s_ = bsrc0 + (size_t)(kb) * 32 * HWSZ;              \
    bregs[slot][0] = *(const uint2*)s_;                                       \
    bregs[slot][1] = *(const uint2*)(s_ + HWSZ);                              \
  } while (0)
#define WRITE_B(slot, buf)                                                    \
  do {                                                                        \
    unsigned int w0_[2] = {bregs[slot][0].x, bregs[slot][0].y};               \
    unsigned int w1_[2] = {bregs[slot][1].x, bregs[slot][1].y};               \
    _Pragma("unroll")                                                         \
    for (int j_ = 0; j_ < 4; ++j_) {                                          \
      int p_ = 4 * pq + j_;                                                   \
      int cc_ = (2 * cp) ^ (SWZ(p_) << 3);                                    \
      unsigned int lo_ = (w0_[j_ >> 1] >> ((j_ & 1) * 16)) & 0xffffu;         \
      unsigned int hi_ = (w1_[j_ >> 1] >> ((j_ & 1) * 16)) & 0xffffu;         \
      *(unsigned int*)&B_lds[buf][p_ * 32 + cc_] = lo_ | (hi_ << 16);         \
    }                                                                         \
  } while (0)

  // ---- prologue: FIFO order A0,B0,A1,B1,B2 (10 vm ops)
  STAGE_A(0, 0);
  LOAD_B(0, 0);
  STAGE_A(1, 1);
  LOAD_B(1, 1);
  LOAD_B(2, 2);

  f32x4 acc[4][4];
#pragma unroll
  for (int mb = 0; mb < 4; ++mb)
#pragma unroll
    for (int nb = 0; nb < 4; ++nb) acc[mb][nb] = (f32x4){0.f, 0.f, 0.f, 0.f};

  // LDS read offsets (elements)
  int aofs[4];
#pragma unroll
  for (int mb = 0; mb < 4; ++mb) aofs[mb] = ((wm * 4 + mb) * 64 + lane) * 8;
  int bofs[4];
#pragma unroll
  for (int nb = 0; nb < 4; ++nb) {
    int pp = wn * 64 + nb * 16 + (lane & 15);
    bofs[nb] = pp * 32 + (((lane >> 4) * 8) ^ (SWZ(pp) << 3));
  }

  // retire A0+B0 (oldest 4 of 10), publish B(0)
  asm volatile("s_waitcnt vmcnt(6)" ::: "memory");
  WRITE_B(0, 0);
  asm volatile("s_waitcnt lgkmcnt(0)" ::: "memory");
  __builtin_amdgcn_s_barrier();              // panel 0 published

#pragma unroll
  for (int kb = 0; kb < 8; ++kb) {
    const int cur = kb % 3;
    const int n1 = (kb + 1) % 3;
    // 1. issue A(kb+2) into LDS buf (kb+2)%3 (released at barrier kb-1),
    //    then B(kb+3) into reg slot (kb+3)&3
    if (kb < 6) STAGE_A(kb + 2, (kb + 2) % 3);
    if (kb < 5) LOAD_B(kb + 3, (kb + 3) & 3);
    if (kb < 6) __builtin_amdgcn_sched_barrier(0);
    // 2. read fragments of panel kb (published)
    short8 af[4], bfr[4];
#pragma unroll
    for (int mb = 0; mb < 4; ++mb)
      af[mb] = *(const short8*)(&A_lds[cur][0] + aofs[mb]);
#pragma unroll
    for (int nb = 0; nb < 4; ++nb)
      bfr[nb] = *(const short8*)(&B_lds[cur][0] + bofs[nb]);
    // 3. retire A(kb+1) [LDS] + B(kb+1) [regs, issued kb-2], publish B(kb+1)
    if (kb <= 4) {
      asm volatile("s_waitcnt vmcnt(6)" ::: "memory");
      WRITE_B((kb + 1) & 3, n1);
    } else if (kb == 5) {
      asm volatile("s_waitcnt vmcnt(4)" ::: "memory");
      WRITE_B((kb + 1) & 3, n1);
    } else if (kb == 6) {
      asm volatile("s_waitcnt vmcnt(0)" ::: "memory");
      WRITE_B((kb + 1) & 3, n1);
    }
    // 4. all LDS ops (frag reads + B writes) complete
    asm volatile("s_waitcnt lgkmcnt(0)" ::: "memory");
    __builtin_amdgcn_sched_barrier(0);
    // 5. MFMA on panel kb (T5)
    __builtin_amdgcn_s_setprio(1);
#pragma unroll
    for (int mb = 0; mb < 4; ++mb)
#pragma unroll
      for (int nb = 0; nb < 4; ++nb)
        acc[mb][nb] = __builtin_amdgcn_mfma_f32_16x16x32_bf16(
            af[mb], bfr[nb], acc[mb][nb], 0, 0, 0);
    __builtin_amdgcn_s_setprio(0);
    // 6. single barrier: publishes panel kb+1, releases buf cur
    if (kb < 7) __builtin_amdgcn_s_barrier();
  }

  // ---- epilogue: bias, y store (bf16, direct), GN partials (no atomics)
  // C/D layout: col(p) = lane&15, row(o) = (lane>>4)*4 + reg
  float psum[2] = {0.f, 0.f}, psq[2] = {0.f, 0.f};
  int orl = (lane >> 4) * 4;
  int pl = lane & 15;
  const size_t ybase = (size_t)bs * CC * HWSZ + p0 + wn * 64;
  int obase = wm * 64;
#pragma unroll
  for (int mb = 0; mb < 4; ++mb) {
    int gi = mb >> 1;                        // wave covers 2 GN groups (64 ch)
#pragma unroll
    for (int r = 0; r < 4; ++r) {
      int o = obase + mb * 16 + orl + r;
      float pb = proj_b[o];
      unsigned short* yrow = yb + ybase + (size_t)o * HWSZ + pl;
#pragma unroll
      for (int nb = 0; nb < 4; ++nb) {
        float v = acc[mb][nb][r] + pb;
        yrow[nb * 16] = f2bf(v);
        psum[gi] += v;
        psq[gi] += v * v;
      }
    }
  }
#pragma unroll
  for (int off = 32; off > 0; off >>= 1) {
#pragma unroll
    for (int k = 0; k < 2; ++k) {
      psum[k] += __shfl_down(psum[k], off, 64);
      psq[k] += __shfl_down(psq[k], off, 64);
    }
  }
  if (lane == 0) {
#pragma unroll
    for (int k = 0; k < 2; ++k) {
      int bg = bs * 8 + wm * 2 + k;
      part[(size_t)bg * 256 + pt * 2 + wn] = psum[k];
      part[32768 + (size_t)bg * 256 + pt * 2 + wn] = psq[k];
    }
  }
#undef STAGE_A
#undef LOAD_B
#undef WRITE_B
}

// ---------------------------------------------------------------------------
// K5: GroupNorm affine + exact GELU + residual, with IN-KERNEL stats reduce.
//     Reads bf16 y + fp32 x, writes fp32 out.
// ---------------------------------------------------------------------------
__global__ __launch_bounds__(256) void out_kernel(
    const float* __restrict__ x, const unsigned short* __restrict__ yb,
    const float* __restrict__ part, const float* __restrict__ gamma,
    const float* __restrict__ beta, float* __restrict__ out) {
  int plane = blockIdx.x;
  int b = plane >> 8, c = plane & 255, g = c >> 5;
  int bg = b * 8 + g;
  int t = threadIdx.x;

  // reduce this group's 256 partials (all threads participate)
  float s = part[(size_t)bg * 256 + t];
  float q = part[32768 + (size_t)bg * 256 + t];
#pragma unroll
  for (int off = 32; off > 0; off >>= 1) {
    s += __shfl_down(s, off, 64);
    q += __shfl_down(q, off, 64);
  }
  __shared__ float ls[8];
  if ((t & 63) == 0) { ls[t >> 6] = s; ls[4 + (t >> 6)] = q; }
  __syncthreads();
  float tsum = ls[0] + ls[1] + ls[2] + ls[3];
  float tsq = ls[4] + ls[5] + ls[6] + ls[7];

  const float inv_n = 1.0f / (32.0f * (float)HWSZ);
  float mean = tsum * inv_n;
  float var = tsq * inv_n - mean * mean;
  float rstd = rsqrtf(var + EPSV);
  float scale = gamma[c] * rstd;
  float shift = beta[c] - mean * scale;

  const size_t base = (size_t)plane * HWSZ;
  for (int i = t; i < HWSZ / 8; i += 256) {
    uint4 yv = *(const uint4*)(yb + base + 8 * (size_t)i);
    float4 x0 = *(const float4*)(x + base + 8 * (size_t)i);
    float4 x1 = *(const float4*)(x + base + 8 * (size_t)i + 4);
    unsigned int yw[4] = {yv.x, yv.y, yv.z, yv.w};
    float r[8];
    float xr[8] = {x0.x, x0.y, x0.z, x0.w, x1.x, x1.y, x1.z, x1.w};
#pragma unroll
    for (int k = 0; k < 8; ++k) {
      unsigned int h = (yw[k >> 1] >> ((k & 1) * 16)) & 0xffffu;
      float tv = bf2f(h) * scale + shift;
      float ge = 0.5f * tv * (1.0f + erff(tv * 0.70710678118654752f));
      r[k] = ge + xr[k];
    }
    *(float4*)(out + base + 8 * (size_t)i) = make_float4(r[0], r[1], r[2], r[3]);
    *(float4*)(out + base + 8 * (size_t)i + 4) = make_float4(r[4], r[5], r[6], r[7]);
  }
}

// ---------------------------------------------------------------------------
extern "C" void kernel_launch(void* const* d_in, const int* in_sizes, int n_in,
                              void* d_out, int out_size, void* d_ws, size_t ws_size,
                              hipStream_t stream) {
  const float* x      = (const float*)d_in[0];
  const float* fbank  = (const float*)d_in[1];   // [NF,1,7,7]
  const float* sel_w  = (const float*)d_in[2];   // [NF,C]
  const float* sel_b  = (const float*)d_in[3];   // [NF]
  const float* proj_w = (const float*)d_in[4];   // [C,C,1,1]
  const float* proj_b = (const float*)d_in[5];   // [C]
  const float* gamma  = (const float*)d_in[6];   // [C]
  const float* beta   = (const float*)d_in[7];   // [C]
  float* out = (float*)d_out;

  // ws layout: fb bf16 [B*C*HW] | yb bf16 [B*C*HW] | ap bf16 [65536]
  //            | pooled | combined | part[65536]
  unsigned short* fb  = (unsigned short*)d_ws;
  unsigned short* yb  = fb + (size_t)BB * CC * HWSZ;
  unsigned short* apk = yb + (size_t)BB * CC * HWSZ;
  float* pooled   = (float*)(apk + 65536);
  float* combined = pooled + BB * CC;
  float* part     = combined + BB * 64;

  hipLaunchKernelGGL(pool_pack_kernel, dim3(BB * CC + 256), dim3(256), 0, stream,
                     x, proj_w, pooled, apk);
  hipLaunchKernelGGL(selector_kernel, dim3(1), dim3(256), 0, stream,
                     pooled, sel_w, sel_b, fbank, combined);
  hipLaunchKernelGGL(dwconv_kernel, dim3(BB * CC, HH / TR), dim3(256), 0, stream,
                     x, combined, fb);
  hipLaunchKernelGGL(gemm_kernel, dim3(BB * 128), dim3(512), 0, stream,
                     fb, apk, proj_b, yb, part);
  hipLaunchKernelGGL(out_kernel, dim3(BB * CC), dim3(256), 0, stream,
                     x, yb, part, gamma, beta, out);
}